// Round 1
// baseline (641.154 us; speedup 1.0000x reference)
//
#include <hip/hip_runtime.h>
#include <math.h>

// GAT layer: N=50000 nodes, E=800000 edges, IN=256, H=4 heads, C=32.
// Pipeline: init_out(bias) + init_nodes -> gemm(h=xW) -> node_dots(al,ar)
//        -> edge pass1 (leaky_relu + seg-max over SRC)
//        -> edge pass2 (exp + seg-sum over SRC)
//        -> edge pass3 (scatter-add into out[DST])  [softmax by src, agg by dst!]
// ws layout (floats): h[N*128] | al[N*4] | ar[N*4] | amax[N*4] | denom[N*4] | alpha[(E+N)*4]
// total ~42.4 MB.

#define NH 4
#define CH 32
#define HC 128
#define IND 256
#define NEG_SLOPE 0.2f

__device__ __forceinline__ void atomicMaxF(float* addr, float val) {
    // Correct for mixed signs when initialized to -inf:
    // positive floats compare correctly as signed ints; negative floats compare
    // reversed as unsigned ints (so atomicMin(uint) = float max). A positive
    // value's uint is always < any negative value's uint, so the two ops never
    // clobber each other incorrectly.
    if (val >= 0.0f) atomicMax((int*)addr, __float_as_int(val));
    else             atomicMin((unsigned int*)addr, __float_as_uint(val));
}

__global__ __launch_bounds__(256) void k_init_out(float* __restrict__ out,
                                                  const float* __restrict__ bias,
                                                  int total) {
    int t = blockIdx.x * 256 + threadIdx.x;
    if (t < total) out[t] = bias[t & (HC - 1)];
}

__global__ __launch_bounds__(256) void k_init_nodes(float* __restrict__ amax,
                                                    float* __restrict__ denom,
                                                    int total) {
    int t = blockIdx.x * 256 + threadIdx.x;
    if (t < total) { amax[t] = -INFINITY; denom[t] = 0.0f; }
}

// h = x @ W : (N x 256) @ (256 x 128). Tile 64 rows x 128 cols per block,
// 256 threads, each computes 8 rows x 4 cols. K staged in 32-chunks in LDS.
__global__ __launch_bounds__(256) void k_gemm(const float* __restrict__ x,
                                              const float* __restrict__ W,
                                              float* __restrict__ h, int N) {
    __shared__ float xs[64 * 33];   // pad 33 to break bank conflicts
    __shared__ float ws[32 * 128];
    const int tid  = threadIdx.x;
    const int row0 = blockIdx.x * 64;
    const int col4 = (tid & 31) * 4;   // 0..124
    const int rowg = tid >> 5;         // 0..7 -> rows rowg*8..rowg*8+7

    float acc[8][4];
#pragma unroll
    for (int i = 0; i < 8; i++)
#pragma unroll
        for (int j = 0; j < 4; j++) acc[i][j] = 0.0f;

    for (int k0 = 0; k0 < IND; k0 += 32) {
        // stage xs: 64 rows x 32 k = 2048 floats (2 x float4 per thread)
#pragma unroll
        for (int j = 0; j < 2; j++) {
            int lin = (tid + j * 256) * 4;   // [0,2048)
            int r   = lin >> 5;
            int kk  = lin & 31;
            int row = row0 + r;
            float4 v = make_float4(0.f, 0.f, 0.f, 0.f);
            if (row < N) v = *(const float4*)(x + (size_t)row * IND + k0 + kk);
            xs[r * 33 + kk + 0] = v.x;
            xs[r * 33 + kk + 1] = v.y;
            xs[r * 33 + kk + 2] = v.z;
            xs[r * 33 + kk + 3] = v.w;
        }
        // stage ws: 32 k x 128 cols = 4096 floats (4 x float4 per thread)
#pragma unroll
        for (int j = 0; j < 4; j++) {
            int lin = (tid + j * 256) * 4;   // [0,4096)
            int kk  = lin >> 7;
            int c   = lin & 127;
            *(float4*)(ws + kk * 128 + c) =
                *(const float4*)(W + (size_t)(k0 + kk) * HC + c);
        }
        __syncthreads();
#pragma unroll
        for (int kk = 0; kk < 32; kk++) {
            float4 wv = *(const float4*)(ws + kk * 128 + col4);
#pragma unroll
            for (int i = 0; i < 8; i++) {
                float xv = xs[(rowg * 8 + i) * 33 + kk];
                acc[i][0] += xv * wv.x;
                acc[i][1] += xv * wv.y;
                acc[i][2] += xv * wv.z;
                acc[i][3] += xv * wv.w;
            }
        }
        __syncthreads();
    }
#pragma unroll
    for (int i = 0; i < 8; i++) {
        int row = row0 + rowg * 8 + i;
        if (row < N)
            *(float4*)(h + (size_t)row * HC + col4) =
                make_float4(acc[i][0], acc[i][1], acc[i][2], acc[i][3]);
    }
}

// al[n][hh] = dot(h[n][hh*32 .. +32], wl[hh]) ; ar likewise with wr.
__global__ __launch_bounds__(256) void k_node_dots(const float* __restrict__ h,
                                                   const float* __restrict__ att,
                                                   float* __restrict__ al,
                                                   float* __restrict__ ar, int N) {
    int t = blockIdx.x * 256 + threadIdx.x;
    if (t >= N * NH) return;
    int n = t >> 2, hh = t & 3;
    const float* hp = h + (size_t)n * HC + hh * CH;
    const float* wl = att + hh * (2 * CH);
    const float* wr = wl + CH;
    float sl = 0.f, sr = 0.f;
#pragma unroll
    for (int c = 0; c < CH; c += 4) {
        float4 hv = *(const float4*)(hp + c);
        float4 lv = *(const float4*)(wl + c);
        float4 rv = *(const float4*)(wr + c);
        sl += hv.x * lv.x + hv.y * lv.y + hv.z * lv.z + hv.w * lv.w;
        sr += hv.x * rv.x + hv.y * rv.y + hv.z * rv.z + hv.w * rv.w;
    }
    al[t] = sl;
    ar[t] = sr;
}

// pass 1: alpha = leaky_relu(al[dst] + ar[src]); amax[src] = max(...)
__global__ __launch_bounds__(256) void k_edge_alpha(const int* __restrict__ ei,
                                                    const float* __restrict__ al,
                                                    const float* __restrict__ ar,
                                                    float* __restrict__ alpha_w,
                                                    float* __restrict__ amax,
                                                    int E, int NE) {
    int t = blockIdx.x * 256 + threadIdx.x;
    if (t >= NE * NH) return;
    int e = t >> 2, hh = t & 3;
    int src, dst;
    if (e < E) { src = ei[e]; dst = ei[E + e]; }
    else       { src = dst = e - E; }
    float a = al[dst * NH + hh] + ar[src * NH + hh];
    a = (a > 0.f) ? a : NEG_SLOPE * a;
    alpha_w[t] = a;
    atomicMaxF(&amax[src * NH + hh], a);
}

// pass 2: alpha = exp(alpha - amax[src]); denom[src] += alpha
__global__ __launch_bounds__(256) void k_edge_exp(const int* __restrict__ ei,
                                                  float* __restrict__ alpha_w,
                                                  const float* __restrict__ amax,
                                                  float* __restrict__ denom,
                                                  int E, int NE) {
    int t = blockIdx.x * 256 + threadIdx.x;
    if (t >= NE * NH) return;
    int e = t >> 2, hh = t & 3;
    int src = (e < E) ? ei[e] : (e - E);
    float a = expf(alpha_w[t] - amax[src * NH + hh]);
    alpha_w[t] = a;
    atomicAdd(&denom[src * NH + hh], a);
}

// pass 3: out[dst][c] += h[src][c] * alpha_e / (denom[src] + 1e-16)
__global__ __launch_bounds__(256) void k_edge_agg(const int* __restrict__ ei,
                                                  const float* __restrict__ hfeat,
                                                  const float* __restrict__ alpha_w,
                                                  const float* __restrict__ denom,
                                                  float* __restrict__ out,
                                                  int E, int NE) {
    unsigned int t = blockIdx.x * 256u + threadIdx.x;
    unsigned int e = t >> 7;
    if (e >= (unsigned int)NE) return;
    int c  = (int)(t & 127u);
    int hh = c >> 5;
    int src, dst;
    if ((int)e < E) { src = ei[e]; dst = ei[E + (int)e]; }
    else            { src = dst = (int)e - E; }
    float w = alpha_w[e * NH + hh] / (denom[src * NH + hh] + 1e-16f);
    atomicAdd(&out[(size_t)dst * HC + c], hfeat[(size_t)src * HC + c] * w);
}

extern "C" void kernel_launch(void* const* d_in, const int* in_sizes, int n_in,
                              void* d_out, int out_size, void* d_ws, size_t ws_size,
                              hipStream_t stream) {
    const float* x    = (const float*)d_in[0];
    const float* W    = (const float*)d_in[1];
    const float* att  = (const float*)d_in[2];
    const float* bias = (const float*)d_in[3];
    const int*   ei   = (const int*)d_in[4];

    const int N  = in_sizes[0] / IND;     // 50000
    const int E  = in_sizes[4] / 2;       // 800000
    const int NE = E + N;                 // edges + self loops
    float* out = (float*)d_out;

    float* h       = (float*)d_ws;
    float* al      = h + (size_t)N * HC;
    float* ar      = al + (size_t)N * NH;
    float* amax    = ar + (size_t)N * NH;
    float* denom   = amax + (size_t)N * NH;
    float* alpha_w = denom + (size_t)N * NH;

    const int outTot  = N * HC;
    const int nodeTot = N * NH;
    const int edgeTot = NE * NH;

    k_init_out<<<(outTot + 255) / 256, 256, 0, stream>>>(out, bias, outTot);
    k_init_nodes<<<(nodeTot + 255) / 256, 256, 0, stream>>>(amax, denom, nodeTot);
    k_gemm<<<(N + 63) / 64, 256, 0, stream>>>(x, W, h, N);
    k_node_dots<<<(nodeTot + 255) / 256, 256, 0, stream>>>(h, att, al, ar, N);
    k_edge_alpha<<<(edgeTot + 255) / 256, 256, 0, stream>>>(ei, al, ar, alpha_w, amax, E, NE);
    k_edge_exp<<<(edgeTot + 255) / 256, 256, 0, stream>>>(ei, alpha_w, amax, denom, E, NE);
    unsigned long long aggTot = (unsigned long long)NE * HC;
    k_edge_agg<<<(unsigned int)((aggTot + 255) / 256), 256, 0, stream>>>(ei, h, alpha_w, denom, out, E, NE);
}

// Round 2
// 476.944 us; speedup vs baseline: 1.3443x; 1.3443x over previous
//
#include <hip/hip_runtime.h>
#include <math.h>

// GAT layer: N=50000, E=800000, IN=256, H=4, C=32.
// R2: replace atomic scatter-add aggregation with dst-CSR gather reduction.
// Pipeline:
//   init(amax,denom,cnt) -> gemm -> node_dots
//   -> edge pass1 (leaky_relu + atomic seg-max over SRC)
//   -> edge pass2 (exp + atomic seg-sum over SRC)
//   -> wnorm (alpha /= denom[src], in place)
//   -> count(dst) -> scan(3 kernels) -> scatter(dst-CSR of {src, e})
//   -> agg_csr: out[n][c] = bias[c] + sum_i h[src_i][c] * wnorm[e_i][hh]

#define NH 4
#define CH 32
#define HC 128
#define IND 256
#define NEG_SLOPE 0.2f

__device__ __forceinline__ void atomicMaxF(float* addr, float val) {
    // positive floats: signed-int max; negative floats: unsigned-int min.
    if (val >= 0.0f) atomicMax((int*)addr, __float_as_int(val));
    else             atomicMin((unsigned int*)addr, __float_as_uint(val));
}

__global__ __launch_bounds__(256) void k_init(float* __restrict__ amax,
                                              float* __restrict__ denom,
                                              int* __restrict__ cnt,
                                              int nodeTot, int N) {
    int t = blockIdx.x * 256 + threadIdx.x;
    if (t < nodeTot) { amax[t] = -INFINITY; denom[t] = 0.0f; }
    if (t < N) cnt[t] = 0;
}

// h = x @ W : (N x 256) @ (256 x 128). 64-row x 128-col tile, 256 threads,
// each thread 8 rows x 4 cols.
__global__ __launch_bounds__(256) void k_gemm(const float* __restrict__ x,
                                              const float* __restrict__ W,
                                              float* __restrict__ h, int N) {
    __shared__ float xs[64 * 33];
    __shared__ float ws[32 * 128];
    const int tid  = threadIdx.x;
    const int row0 = blockIdx.x * 64;
    const int col4 = (tid & 31) * 4;
    const int rowg = tid >> 5;

    float acc[8][4];
#pragma unroll
    for (int i = 0; i < 8; i++)
#pragma unroll
        for (int j = 0; j < 4; j++) acc[i][j] = 0.0f;

    for (int k0 = 0; k0 < IND; k0 += 32) {
#pragma unroll
        for (int j = 0; j < 2; j++) {
            int lin = (tid + j * 256) * 4;
            int r   = lin >> 5;
            int kk  = lin & 31;
            int row = row0 + r;
            float4 v = make_float4(0.f, 0.f, 0.f, 0.f);
            if (row < N) v = *(const float4*)(x + (size_t)row * IND + k0 + kk);
            xs[r * 33 + kk + 0] = v.x;
            xs[r * 33 + kk + 1] = v.y;
            xs[r * 33 + kk + 2] = v.z;
            xs[r * 33 + kk + 3] = v.w;
        }
#pragma unroll
        for (int j = 0; j < 4; j++) {
            int lin = (tid + j * 256) * 4;
            int kk  = lin >> 7;
            int c   = lin & 127;
            *(float4*)(ws + kk * 128 + c) =
                *(const float4*)(W + (size_t)(k0 + kk) * HC + c);
        }
        __syncthreads();
#pragma unroll
        for (int kk = 0; kk < 32; kk++) {
            float4 wv = *(const float4*)(ws + kk * 128 + col4);
#pragma unroll
            for (int i = 0; i < 8; i++) {
                float xv = xs[(rowg * 8 + i) * 33 + kk];
                acc[i][0] += xv * wv.x;
                acc[i][1] += xv * wv.y;
                acc[i][2] += xv * wv.z;
                acc[i][3] += xv * wv.w;
            }
        }
        __syncthreads();
    }
#pragma unroll
    for (int i = 0; i < 8; i++) {
        int row = row0 + rowg * 8 + i;
        if (row < N)
            *(float4*)(h + (size_t)row * HC + col4) =
                make_float4(acc[i][0], acc[i][1], acc[i][2], acc[i][3]);
    }
}

__global__ __launch_bounds__(256) void k_node_dots(const float* __restrict__ h,
                                                   const float* __restrict__ att,
                                                   float* __restrict__ al,
                                                   float* __restrict__ ar, int N) {
    int t = blockIdx.x * 256 + threadIdx.x;
    if (t >= N * NH) return;
    int n = t >> 2, hh = t & 3;
    const float* hp = h + (size_t)n * HC + hh * CH;
    const float* wl = att + hh * (2 * CH);
    const float* wr = wl + CH;
    float sl = 0.f, sr = 0.f;
#pragma unroll
    for (int c = 0; c < CH; c += 4) {
        float4 hv = *(const float4*)(hp + c);
        float4 lv = *(const float4*)(wl + c);
        float4 rv = *(const float4*)(wr + c);
        sl += hv.x * lv.x + hv.y * lv.y + hv.z * lv.z + hv.w * lv.w;
        sr += hv.x * rv.x + hv.y * rv.y + hv.z * rv.z + hv.w * rv.w;
    }
    al[t] = sl;
    ar[t] = sr;
}

__global__ __launch_bounds__(256) void k_edge_alpha(const int* __restrict__ ei,
                                                    const float* __restrict__ al,
                                                    const float* __restrict__ ar,
                                                    float* __restrict__ alpha_w,
                                                    float* __restrict__ amax,
                                                    int E, int NE) {
    int t = blockIdx.x * 256 + threadIdx.x;
    if (t >= NE * NH) return;
    int e = t >> 2, hh = t & 3;
    int src, dst;
    if (e < E) { src = ei[e]; dst = ei[E + e]; }
    else       { src = dst = e - E; }
    float a = al[dst * NH + hh] + ar[src * NH + hh];
    a = (a > 0.f) ? a : NEG_SLOPE * a;
    alpha_w[t] = a;
    atomicMaxF(&amax[src * NH + hh], a);
}

__global__ __launch_bounds__(256) void k_edge_exp(const int* __restrict__ ei,
                                                  float* __restrict__ alpha_w,
                                                  const float* __restrict__ amax,
                                                  float* __restrict__ denom,
                                                  int E, int NE) {
    int t = blockIdx.x * 256 + threadIdx.x;
    if (t >= NE * NH) return;
    int e = t >> 2, hh = t & 3;
    int src = (e < E) ? ei[e] : (e - E);
    float a = expf(alpha_w[t] - amax[src * NH + hh]);
    alpha_w[t] = a;
    atomicAdd(&denom[src * NH + hh], a);
}

// alpha_w[t] /= denom[src] + eps  (in place)
__global__ __launch_bounds__(256) void k_wnorm(const int* __restrict__ ei,
                                               float* __restrict__ alpha_w,
                                               const float* __restrict__ denom,
                                               int E, int NE) {
    int t = blockIdx.x * 256 + threadIdx.x;
    if (t >= NE * NH) return;
    int e = t >> 2, hh = t & 3;
    int src = (e < E) ? ei[e] : (e - E);
    alpha_w[t] = alpha_w[t] / (denom[src * NH + hh] + 1e-16f);
}

__global__ __launch_bounds__(256) void k_count(const int* __restrict__ ei,
                                               int* __restrict__ cnt,
                                               int E, int NE) {
    int t = blockIdx.x * 256 + threadIdx.x;
    if (t >= NE) return;
    int dst = (t < E) ? ei[E + t] : (t - E);
    atomicAdd(&cnt[dst], 1);
}

// ---- 3-kernel exclusive scan of cnt[N] -> rowptr[N], bsums gets block offsets
__global__ __launch_bounds__(256) void k_scan1(const int* __restrict__ cnt,
                                               int* __restrict__ excl,
                                               int* __restrict__ bsums, int N) {
    __shared__ int lds[256];
    int tid  = threadIdx.x;
    int base = blockIdx.x * 1024 + tid * 4;
    int v0 = (base + 0 < N) ? cnt[base + 0] : 0;
    int v1 = (base + 1 < N) ? cnt[base + 1] : 0;
    int v2 = (base + 2 < N) ? cnt[base + 2] : 0;
    int v3 = (base + 3 < N) ? cnt[base + 3] : 0;
    int e1 = v0, e2 = v0 + v1, e3 = v0 + v1 + v2;
    int tot = e3 + v3;
    lds[tid] = tot;
    __syncthreads();
    for (int off = 1; off < 256; off <<= 1) {
        int t = (tid >= off) ? lds[tid - off] : 0;
        __syncthreads();
        lds[tid] += t;
        __syncthreads();
    }
    int exoff = lds[tid] - tot;
    if (base + 0 < N) excl[base + 0] = exoff;
    if (base + 1 < N) excl[base + 1] = exoff + e1;
    if (base + 2 < N) excl[base + 2] = exoff + e2;
    if (base + 3 < N) excl[base + 3] = exoff + e3;
    if (tid == 255) bsums[blockIdx.x] = lds[255];
}

__global__ __launch_bounds__(256) void k_scan2(int* __restrict__ bsums, int nb) {
    __shared__ int lds[256];
    int tid = threadIdx.x;
    int v = (tid < nb) ? bsums[tid] : 0;
    lds[tid] = v;
    __syncthreads();
    for (int off = 1; off < 256; off <<= 1) {
        int t = (tid >= off) ? lds[tid - off] : 0;
        __syncthreads();
        lds[tid] += t;
        __syncthreads();
    }
    if (tid < nb) bsums[tid] = lds[tid] - v;
}

__global__ __launch_bounds__(256) void k_scan3(int* __restrict__ rowptr,
                                               int* __restrict__ woff,
                                               const int* __restrict__ bsums,
                                               int N, int NE) {
    int t = blockIdx.x * 256 + threadIdx.x;
    if (t < N) {
        int v = rowptr[t] + bsums[t >> 10];
        rowptr[t] = v;
        woff[t]   = v;
    }
    if (t == 0) rowptr[N] = NE;
}

__global__ __launch_bounds__(256) void k_scatter(const int* __restrict__ ei,
                                                 int* __restrict__ woff,
                                                 int2* __restrict__ elist,
                                                 int E, int NE) {
    int t = blockIdx.x * 256 + threadIdx.x;
    if (t >= NE) return;
    int src, dst;
    if (t < E) { src = ei[t]; dst = ei[E + t]; }
    else       { src = dst = t - E; }
    int pos = atomicAdd(&woff[dst], 1);
    elist[pos] = make_int2(src, t);
}

// out[n][c] = bias[c] + sum over incident edges: h[src][c] * wnorm[e][hh]
// 256 threads / block = 2 nodes (128 channels each).
__global__ __launch_bounds__(256) void k_agg_csr(const int* __restrict__ rowptr,
                                                 const int2* __restrict__ elist,
                                                 const float* __restrict__ h,
                                                 const float* __restrict__ wn,
                                                 const float* __restrict__ bias,
                                                 float* __restrict__ out, int N) {
    int n = blockIdx.x * 2 + (threadIdx.x >> 7);
    if (n >= N) return;
    int c  = threadIdx.x & 127;
    int hh = c >> 5;
    int beg = rowptr[n], end = rowptr[n + 1];
    float acc0 = bias[c], acc1 = 0.f;
    int i = beg;
    for (; i + 2 <= end; i += 2) {
        int2 a = elist[i];
        int2 b = elist[i + 1];
        float w0 = wn[a.y * NH + hh];
        float w1 = wn[b.y * NH + hh];
        acc0 += h[(size_t)a.x * HC + c] * w0;
        acc1 += h[(size_t)b.x * HC + c] * w1;
    }
    if (i < end) {
        int2 a = elist[i];
        acc0 += h[(size_t)a.x * HC + c] * wn[a.y * NH + hh];
    }
    out[(size_t)n * HC + c] = acc0 + acc1;
}

extern "C" void kernel_launch(void* const* d_in, const int* in_sizes, int n_in,
                              void* d_out, int out_size, void* d_ws, size_t ws_size,
                              hipStream_t stream) {
    const float* x    = (const float*)d_in[0];
    const float* W    = (const float*)d_in[1];
    const float* att  = (const float*)d_in[2];
    const float* bias = (const float*)d_in[3];
    const int*   ei   = (const int*)d_in[4];

    const int N  = in_sizes[0] / IND;     // 50000
    const int E  = in_sizes[4] / 2;       // 800000
    const int NE = E + N;
    float* out = (float*)d_out;

    // ws layout (element offsets, all 8B-aligned)
    float* h       = (float*)d_ws;                       // N*128
    float* al      = h + (size_t)N * HC;                 // N*4
    float* ar      = al + (size_t)N * NH;                // N*4
    float* amax    = ar + (size_t)N * NH;                // N*4
    float* denom   = amax + (size_t)N * NH;              // N*4
    float* alpha_w = denom + (size_t)N * NH;             // NE*4
    int*   cnt     = (int*)(alpha_w + (size_t)NE * NH);  // N
    int*   rowptr  = cnt + N;                            // N+1 (+1 pad)
    int*   woff    = rowptr + (N + 2);                   // N
    int*   bsums   = woff + N;                           // 256
    int2*  elist   = (int2*)(bsums + 256);               // NE

    const int nodeTot = N * NH;
    const int edgeTot = NE * NH;
    const int nb1     = (N + 1023) / 1024;

    k_init<<<(nodeTot + 255) / 256, 256, 0, stream>>>(amax, denom, cnt, nodeTot, N);
    k_gemm<<<(N + 63) / 64, 256, 0, stream>>>(x, W, h, N);
    k_node_dots<<<(nodeTot + 255) / 256, 256, 0, stream>>>(h, att, al, ar, N);
    k_edge_alpha<<<(edgeTot + 255) / 256, 256, 0, stream>>>(ei, al, ar, alpha_w, amax, E, NE);
    k_edge_exp<<<(edgeTot + 255) / 256, 256, 0, stream>>>(ei, alpha_w, amax, denom, E, NE);
    k_wnorm<<<(edgeTot + 255) / 256, 256, 0, stream>>>(ei, alpha_w, denom, E, NE);
    k_count<<<(NE + 255) / 256, 256, 0, stream>>>(ei, cnt, E, NE);
    k_scan1<<<nb1, 256, 0, stream>>>(cnt, rowptr, bsums, N);
    k_scan2<<<1, 256, 0, stream>>>(bsums, nb1);
    k_scan3<<<(N + 255) / 256, 256, 0, stream>>>(rowptr, woff, bsums, N, NE);
    k_scatter<<<(NE + 255) / 256, 256, 0, stream>>>(ei, woff, elist, E, NE);
    k_agg_csr<<<(N + 1) / 2, 256, 0, stream>>>(rowptr, elist, h, alpha_w, bias, out, N);
}

// Round 3
// 330.578 us; speedup vs baseline: 1.9395x; 1.4428x over previous
//
#include <hip/hip_runtime.h>
#include <math.h>

// GAT layer: N=50000, E=800000, IN=256, H=4, C=32.
// R3: bf16 h for gathers; no segment-max (exp(a)/sum exp(a) is safe here);
//     no materialized alpha; per-edge float4 weights built in scatter.
// Pipeline:
//   init(denom,cnt) -> gemm(h_bf = bf16(x@W)) -> node_dots(al,ar from h_bf)
//   -> edge passA: p=exp(leaky(al[dst]+ar[src])); denom[src]+=p; cnt[dst]++ (hh0)
//   -> scan1/2/3 (dst-CSR rowptr)
//   -> scatter: pos=woff[dst]++; elist[pos]=src; wlist[pos]=p4/denom4[src]
//   -> agg: out[n][c] = bias[c] + sum_i bf2f(h_bf[src_i][c]) * wlist[i][hh]

#define NH 4
#define CH 32
#define HC 128
#define IND 256
#define NEG_SLOPE 0.2f

__device__ __forceinline__ unsigned short f2bf(float f) {
    unsigned int u = __float_as_uint(f);
    unsigned int r = (u + 0x7FFFu + ((u >> 16) & 1u)) >> 16;   // RNE
    return (unsigned short)r;
}
__device__ __forceinline__ float bf2f(unsigned short s) {
    return __uint_as_float(((unsigned int)s) << 16);
}

__global__ __launch_bounds__(256) void k_init(float* __restrict__ denom,
                                              int* __restrict__ cnt,
                                              int nodeTot, int N) {
    int t = blockIdx.x * 256 + threadIdx.x;
    if (t < nodeTot) denom[t] = 0.0f;
    if (t < N) cnt[t] = 0;
}

// h_bf = bf16(x @ W) : (N x 256) @ (256 x 128), fp32 accumulate.
__global__ __launch_bounds__(256) void k_gemm(const float* __restrict__ x,
                                              const float* __restrict__ W,
                                              unsigned short* __restrict__ h_bf,
                                              int N) {
    __shared__ float xs[64 * 33];
    __shared__ float ws[32 * 128];
    const int tid  = threadIdx.x;
    const int row0 = blockIdx.x * 64;
    const int col4 = (tid & 31) * 4;
    const int rowg = tid >> 5;

    float acc[8][4];
#pragma unroll
    for (int i = 0; i < 8; i++)
#pragma unroll
        for (int j = 0; j < 4; j++) acc[i][j] = 0.0f;

    for (int k0 = 0; k0 < IND; k0 += 32) {
#pragma unroll
        for (int j = 0; j < 2; j++) {
            int lin = (tid + j * 256) * 4;
            int r   = lin >> 5;
            int kk  = lin & 31;
            int row = row0 + r;
            float4 v = make_float4(0.f, 0.f, 0.f, 0.f);
            if (row < N) v = *(const float4*)(x + (size_t)row * IND + k0 + kk);
            xs[r * 33 + kk + 0] = v.x;
            xs[r * 33 + kk + 1] = v.y;
            xs[r * 33 + kk + 2] = v.z;
            xs[r * 33 + kk + 3] = v.w;
        }
#pragma unroll
        for (int j = 0; j < 4; j++) {
            int lin = (tid + j * 256) * 4;
            int kk  = lin >> 7;
            int c   = lin & 127;
            *(float4*)(ws + kk * 128 + c) =
                *(const float4*)(W + (size_t)(k0 + kk) * HC + c);
        }
        __syncthreads();
#pragma unroll
        for (int kk = 0; kk < 32; kk++) {
            float4 wv = *(const float4*)(ws + kk * 128 + col4);
#pragma unroll
            for (int i = 0; i < 8; i++) {
                float xv = xs[(rowg * 8 + i) * 33 + kk];
                acc[i][0] += xv * wv.x;
                acc[i][1] += xv * wv.y;
                acc[i][2] += xv * wv.z;
                acc[i][3] += xv * wv.w;
            }
        }
        __syncthreads();
    }
#pragma unroll
    for (int i = 0; i < 8; i++) {
        int row = row0 + rowg * 8 + i;
        if (row < N) {
            ushort4 o;
            o.x = f2bf(acc[i][0]);
            o.y = f2bf(acc[i][1]);
            o.z = f2bf(acc[i][2]);
            o.w = f2bf(acc[i][3]);
            *(ushort4*)(h_bf + (size_t)row * HC + col4) = o;
        }
    }
}

__global__ __launch_bounds__(256) void k_node_dots(const unsigned short* __restrict__ h_bf,
                                                   const float* __restrict__ att,
                                                   float* __restrict__ al,
                                                   float* __restrict__ ar, int N) {
    int t = blockIdx.x * 256 + threadIdx.x;
    if (t >= N * NH) return;
    int n = t >> 2, hh = t & 3;
    const unsigned short* hp = h_bf + (size_t)n * HC + hh * CH;
    const float* wl = att + hh * (2 * CH);
    const float* wr = wl + CH;
    float sl = 0.f, sr = 0.f;
#pragma unroll
    for (int c = 0; c < CH; c += 4) {
        ushort4 hv = *(const ushort4*)(hp + c);
        float4  lv = *(const float4*)(wl + c);
        float4  rv = *(const float4*)(wr + c);
        float h0 = bf2f(hv.x), h1 = bf2f(hv.y), h2 = bf2f(hv.z), h3 = bf2f(hv.w);
        sl += h0 * lv.x + h1 * lv.y + h2 * lv.z + h3 * lv.w;
        sr += h0 * rv.x + h1 * rv.y + h2 * rv.z + h3 * rv.w;
    }
    al[t] = sl;
    ar[t] = sr;
}

// pass A: p = exp(leaky(al[dst]+ar[src])); denom[src] += p; cnt[dst]++ (hh==0)
__global__ __launch_bounds__(256) void k_edge_pA(const int* __restrict__ ei,
                                                 const float* __restrict__ al,
                                                 const float* __restrict__ ar,
                                                 float* __restrict__ denom,
                                                 int* __restrict__ cnt,
                                                 int E, int NE) {
    int t = blockIdx.x * 256 + threadIdx.x;
    if (t >= NE * NH) return;
    int e = t >> 2, hh = t & 3;
    int src, dst;
    if (e < E) { src = ei[e]; dst = ei[E + e]; }
    else       { src = dst = e - E; }
    float a = al[dst * NH + hh] + ar[src * NH + hh];
    a = (a > 0.f) ? a : NEG_SLOPE * a;
    float p = __expf(a);
    atomicAdd(&denom[src * NH + hh], p);
    if (hh == 0) atomicAdd(&cnt[dst], 1);
}

// ---- 3-kernel exclusive scan of cnt[N]
__global__ __launch_bounds__(256) void k_scan1(const int* __restrict__ cnt,
                                               int* __restrict__ excl,
                                               int* __restrict__ bsums, int N) {
    __shared__ int lds[256];
    int tid  = threadIdx.x;
    int base = blockIdx.x * 1024 + tid * 4;
    int v0 = (base + 0 < N) ? cnt[base + 0] : 0;
    int v1 = (base + 1 < N) ? cnt[base + 1] : 0;
    int v2 = (base + 2 < N) ? cnt[base + 2] : 0;
    int v3 = (base + 3 < N) ? cnt[base + 3] : 0;
    int e1 = v0, e2 = v0 + v1, e3 = v0 + v1 + v2;
    int tot = e3 + v3;
    lds[tid] = tot;
    __syncthreads();
    for (int off = 1; off < 256; off <<= 1) {
        int t = (tid >= off) ? lds[tid - off] : 0;
        __syncthreads();
        lds[tid] += t;
        __syncthreads();
    }
    int exoff = lds[tid] - tot;
    if (base + 0 < N) excl[base + 0] = exoff;
    if (base + 1 < N) excl[base + 1] = exoff + e1;
    if (base + 2 < N) excl[base + 2] = exoff + e2;
    if (base + 3 < N) excl[base + 3] = exoff + e3;
    if (tid == 255) bsums[blockIdx.x] = lds[255];
}

__global__ __launch_bounds__(256) void k_scan2(int* __restrict__ bsums, int nb) {
    __shared__ int lds[256];
    int tid = threadIdx.x;
    int v = (tid < nb) ? bsums[tid] : 0;
    lds[tid] = v;
    __syncthreads();
    for (int off = 1; off < 256; off <<= 1) {
        int t = (tid >= off) ? lds[tid - off] : 0;
        __syncthreads();
        lds[tid] += t;
        __syncthreads();
    }
    if (tid < nb) bsums[tid] = lds[tid] - v;
}

__global__ __launch_bounds__(256) void k_scan3(int* __restrict__ rowptr,
                                               int* __restrict__ woff,
                                               const int* __restrict__ bsums,
                                               int N, int NE) {
    int t = blockIdx.x * 256 + threadIdx.x;
    if (t < N) {
        int v = rowptr[t] + bsums[t >> 10];
        rowptr[t] = v;
        woff[t]   = v;
    }
    if (t == 0) rowptr[N] = NE;
}

// scatter: recompute p, divide by denom[src], store {src} + float4 weights.
__global__ __launch_bounds__(256) void k_scatter(const int* __restrict__ ei,
                                                 const float* __restrict__ al,
                                                 const float* __restrict__ ar,
                                                 const float* __restrict__ denom,
                                                 int* __restrict__ woff,
                                                 int* __restrict__ elist,
                                                 float4* __restrict__ wlist,
                                                 int E, int NE) {
    int t = blockIdx.x * 256 + threadIdx.x;
    if (t >= NE) return;
    int src, dst;
    if (t < E) { src = ei[t]; dst = ei[E + t]; }
    else       { src = dst = t - E; }
    float4 av = *(const float4*)(al + dst * NH);
    float4 rv = *(const float4*)(ar + src * NH);
    float4 dv = *(const float4*)(denom + src * NH);
    float a0 = av.x + rv.x, a1 = av.y + rv.y, a2 = av.z + rv.z, a3 = av.w + rv.w;
    a0 = (a0 > 0.f) ? a0 : NEG_SLOPE * a0;
    a1 = (a1 > 0.f) ? a1 : NEG_SLOPE * a1;
    a2 = (a2 > 0.f) ? a2 : NEG_SLOPE * a2;
    a3 = (a3 > 0.f) ? a3 : NEG_SLOPE * a3;
    float4 w;
    w.x = __expf(a0) / (dv.x + 1e-16f);
    w.y = __expf(a1) / (dv.y + 1e-16f);
    w.z = __expf(a2) / (dv.z + 1e-16f);
    w.w = __expf(a3) / (dv.w + 1e-16f);
    int pos = atomicAdd(&woff[dst], 1);
    elist[pos] = src;
    wlist[pos] = w;
}

// agg: 4 nodes/block, 64 threads/node, 2 channels/thread (ushort2 loads).
__global__ __launch_bounds__(256) void k_agg(const int* __restrict__ rowptr,
                                             const int* __restrict__ elist,
                                             const float* __restrict__ wlist,
                                             const unsigned short* __restrict__ h_bf,
                                             const float* __restrict__ bias,
                                             float* __restrict__ out, int N) {
    int n = blockIdx.x * 4 + (threadIdx.x >> 6);
    if (n >= N) return;
    int lane = threadIdx.x & 63;
    int c    = lane * 2;           // c, c+1 (same head: c even)
    int hh   = lane >> 4;          // c>>5
    int beg = rowptr[n], end = rowptr[n + 1];
    float a0 = bias[c], a1 = bias[c + 1];
    float b0 = 0.f, b1 = 0.f;
    int i = beg;
    for (; i + 2 <= end; i += 2) {
        int s0 = elist[i];
        int s1 = elist[i + 1];
        float w0 = wlist[i * 4 + hh];
        float w1 = wlist[(i + 1) * 4 + hh];
        ushort2 u0 = *(const ushort2*)(h_bf + (size_t)s0 * HC + c);
        ushort2 u1 = *(const ushort2*)(h_bf + (size_t)s1 * HC + c);
        a0 += bf2f(u0.x) * w0;
        a1 += bf2f(u0.y) * w0;
        b0 += bf2f(u1.x) * w1;
        b1 += bf2f(u1.y) * w1;
    }
    if (i < end) {
        int s0 = elist[i];
        float w0 = wlist[i * 4 + hh];
        ushort2 u0 = *(const ushort2*)(h_bf + (size_t)s0 * HC + c);
        a0 += bf2f(u0.x) * w0;
        a1 += bf2f(u0.y) * w0;
    }
    *(float2*)(out + (size_t)n * HC + c) = make_float2(a0 + b0, a1 + b1);
}

extern "C" void kernel_launch(void* const* d_in, const int* in_sizes, int n_in,
                              void* d_out, int out_size, void* d_ws, size_t ws_size,
                              hipStream_t stream) {
    const float* x    = (const float*)d_in[0];
    const float* W    = (const float*)d_in[1];
    const float* att  = (const float*)d_in[2];
    const float* bias = (const float*)d_in[3];
    const int*   ei   = (const int*)d_in[4];

    const int N  = in_sizes[0] / IND;     // 50000
    const int E  = in_sizes[4] / 2;       // 800000
    const int NE = E + N;
    float* out = (float*)d_out;

    // ws layout
    unsigned short* h_bf = (unsigned short*)d_ws;            // N*128 ushort (12.8MB)
    float4* wlist  = (float4*)(h_bf + (size_t)N * HC);       // NE float4 (13.6MB)
    float*  al     = (float*)(wlist + NE);                   // N*4
    float*  ar     = al + (size_t)N * NH;                    // N*4
    float*  denom  = ar + (size_t)N * NH;                    // N*4
    int*    cnt    = (int*)(denom + (size_t)N * NH);         // N
    int*    rowptr = cnt + N;                                // N+1 (+pad)
    int*    woff   = rowptr + (N + 2);                       // N
    int*    bsums  = woff + N;                               // 256
    int*    elist  = bsums + 256;                            // NE

    const int nodeTot = N * NH;
    const int edgeTot = NE * NH;
    const int nb1     = (N + 1023) / 1024;

    k_init<<<(nodeTot + 255) / 256, 256, 0, stream>>>(denom, cnt, nodeTot, N);
    k_gemm<<<(N + 63) / 64, 256, 0, stream>>>(x, W, h_bf, N);
    k_node_dots<<<(nodeTot + 255) / 256, 256, 0, stream>>>(h_bf, att, al, ar, N);
    k_edge_pA<<<(edgeTot + 255) / 256, 256, 0, stream>>>(ei, al, ar, denom, cnt, E, NE);
    k_scan1<<<nb1, 256, 0, stream>>>(cnt, rowptr, bsums, N);
    k_scan2<<<1, 256, 0, stream>>>(bsums, nb1);
    k_scan3<<<(N + 255) / 256, 256, 0, stream>>>(rowptr, woff, bsums, N, NE);
    k_scatter<<<(NE + 255) / 256, 256, 0, stream>>>(ei, al, ar, denom, woff, elist, wlist, E, NE);
    k_agg<<<(N + 3) / 4, 256, 0, stream>>>(rowptr, elist, (const float*)wlist, h_bf, bias, out, N);
}